// Round 1
// baseline (2371.337 us; speedup 1.0000x reference)
//
#include <hip/hip_runtime.h>
#include <math.h>

// PixelSnail forward, fp32 baseline.
// Shapes: B=8, CH=1, H=W=32 (N=1024 pixels), HID=64, S=8 stages, L=2 blocks,
// HEAD=4, QK=16 (d=4/head), VD=32 (8/head).

#define NPix 1024

__device__ __forceinline__ float elu_f(float x){ return x > 0.f ? x : expm1f(x); }

// ---------------- stem: masked 3x3 conv, 1->64, taps (0,0)(0,1)(0,2)(1,0) ----
__global__ __launch_bounds__(256) void k_stem(const float* __restrict__ x,
        const float* __restrict__ w, const float* __restrict__ bias,
        float* __restrict__ out, float* __restrict__ e_out)
{
    int idx = blockIdx.x*256 + threadIdx.x;      // b*N + hw, grid 32*256 = 8192
    int b = idx >> 10, hw = idx & 1023;
    int h = hw >> 5, c = hw & 31;
    const float* xb = x + b*NPix;
    float x00=0.f, x01=0.f, x02=0.f, x10=0.f;
    if (h > 0){
        if (c > 0)  x00 = xb[hw-33];
        x01 = xb[hw-32];
        if (c < 31) x02 = xb[hw-31];
    }
    if (c > 0) x10 = xb[hw-1];
    for (int o=0;o<64;o++){
        const float* wo = w + o*9;               // [o][0][3][3]
        float v = bias[o] + wo[0]*x00 + wo[1]*x01 + wo[2]*x02 + wo[3]*x10;
        out[(b*64+o)*NPix + hw] = v;
        e_out[(b*64+o)*NPix + hw] = elu_f(v);
    }
}

// ---------------- basic-block conv1: elu'd input, 2x2 causal conv 64->64, out = elu ----
__global__ __launch_bounds__(256) void k_bbA(const float* __restrict__ ein,
        const float* __restrict__ w, const float* __restrict__ bias,
        float* __restrict__ t1e)
{
    __shared__ float eld[2*64*33];               // [r(h-1,h)][i][col -1..31]
    int b = blockIdx.x >> 5;                     // grid = 8*32
    int h = blockIdx.x & 31;
    int t = threadIdx.x;
    for (int idx = t; idx < 2*64*33; idx += 256){
        int cpos = idx % 33;
        int ri = idx / 33;
        int r = ri >> 6, i = ri & 63;
        int row = h - 1 + r, col = cpos - 1;
        float v = 0.f;
        if (row >= 0 && col >= 0) v = ein[(b*64+i)*NPix + row*32 + col];
        eld[idx] = v;
    }
    __syncthreads();
    int col  = t & 31;
    int slot = t >> 5;                           // 8 output channels per thread
    float acc[8];
    #pragma unroll
    for (int k2=0;k2<8;k2++) acc[k2] = bias[slot*8+k2];
    const float* wbase = w + slot*8*64*4;        // [o][i][2][2]
    for (int i=0;i<64;i++){
        float e00 = eld[i*33 + col];
        float e01 = eld[i*33 + col + 1];
        float e10 = eld[(64+i)*33 + col];
        float e11 = eld[(64+i)*33 + col + 1];
        #pragma unroll
        for (int k2=0;k2<8;k2++){
            float4 wv = *reinterpret_cast<const float4*>(wbase + (k2*64 + i)*4);
            acc[k2] = fmaf(wv.x, e00, acc[k2]);
            acc[k2] = fmaf(wv.y, e01, acc[k2]);
            acc[k2] = fmaf(wv.z, e10, acc[k2]);
            acc[k2] = fmaf(wv.w, e11, acc[k2]);
        }
    }
    int base = b*64*NPix + h*32 + col;
    #pragma unroll
    for (int k2=0;k2<8;k2++)
        t1e[base + (slot*8+k2)*NPix] = elu_f(acc[k2]);
}

// ---------------- basic-block conv2 + gate: elu'd input, 2x2 conv 64->128, x + x1*sig(x2) ----
__global__ __launch_bounds__(256) void k_bbB(const float* __restrict__ ein,
        const float* __restrict__ xres,
        const float* __restrict__ w, const float* __restrict__ bias,
        float* __restrict__ conv_out, float* __restrict__ e_out)
{
    __shared__ float eld[2*64*33];
    __shared__ float obuf[128*32];
    int b = blockIdx.x >> 5;
    int h = blockIdx.x & 31;
    int t = threadIdx.x;
    for (int idx = t; idx < 2*64*33; idx += 256){
        int cpos = idx % 33;
        int ri = idx / 33;
        int r = ri >> 6, i = ri & 63;
        int row = h - 1 + r, col = cpos - 1;
        float v = 0.f;
        if (row >= 0 && col >= 0) v = ein[(b*64+i)*NPix + row*32 + col];
        eld[idx] = v;
    }
    __syncthreads();
    int col  = t & 31;
    int slot = t >> 5;                           // 16 output channels per thread
    float acc[16];
    #pragma unroll
    for (int k2=0;k2<16;k2++) acc[k2] = bias[slot*16+k2];
    const float* wbase = w + slot*16*64*4;       // [128][64][2][2]
    for (int i=0;i<64;i++){
        float e00 = eld[i*33 + col];
        float e01 = eld[i*33 + col + 1];
        float e10 = eld[(64+i)*33 + col];
        float e11 = eld[(64+i)*33 + col + 1];
        #pragma unroll
        for (int k2=0;k2<16;k2++){
            float4 wv = *reinterpret_cast<const float4*>(wbase + (k2*64 + i)*4);
            acc[k2] = fmaf(wv.x, e00, acc[k2]);
            acc[k2] = fmaf(wv.y, e01, acc[k2]);
            acc[k2] = fmaf(wv.z, e10, acc[k2]);
            acc[k2] = fmaf(wv.w, e11, acc[k2]);
        }
    }
    #pragma unroll
    for (int k2=0;k2<16;k2++) obuf[(slot*16+k2)*32 + col] = acc[k2];
    __syncthreads();
    for (int idx = t; idx < 64*32; idx += 256){
        int o = idx >> 5, c2 = idx & 31;
        float x1 = obuf[o*32 + c2], x2 = obuf[(o+64)*32 + c2];
        int gi = (b*64+o)*NPix + h*32 + c2;
        float v = fmaf(x1, 1.f/(1.f + expf(-x2)), xres[gi]);
        conv_out[gi] = v;
        e_out[gi] = elu_f(v);
    }
}

// ---------------- qkv 1x1 conv: (conv_raw 64ch + pos 2ch) -> q/k/v head layouts ----
__global__ __launch_bounds__(256) void k_qkv(const float* __restrict__ conv,
        const float* __restrict__ w, const float* __restrict__ bias,
        float* __restrict__ qb, float* __restrict__ kb, float* __restrict__ vb)
{
    __shared__ float cl[64*64];                  // [i][px]
    int b = blockIdx.x >> 4;                     // grid 128: 16 blocks/image of 64 px
    int hwbase = (blockIdx.x & 15) * 64;
    int t = threadIdx.x;
    for (int idx = t; idx < 64*64; idx += 256){
        int i = idx >> 6, p = idx & 63;
        cl[idx] = conv[(b*64+i)*NPix + hwbase + p];
    }
    __syncthreads();
    int px = t & 63, part = t >> 6;              // wave-uniform part, 16 outputs each
    int hw = hwbase + px;
    float py  = (float)(hw >> 5) * (1.f/32.f) - 0.5f;
    float pxc = (float)(hw & 31) * (1.f/32.f) - 0.5f;
    int c0 = part*16;
    float acc[16];
    #pragma unroll
    for (int k2=0;k2<16;k2++){
        const float* wr = w + (c0+k2)*66;
        acc[k2] = bias[c0+k2] + wr[64]*py + wr[65]*pxc;
    }
    for (int i=0;i<64;i++){
        float e = cl[i*64 + px];
        #pragma unroll
        for (int k2=0;k2<16;k2++)
            acc[k2] = fmaf(w[(c0+k2)*66 + i], e, acc[k2]);
    }
    if (part == 0){
        #pragma unroll
        for (int k2=0;k2<16;k2++)   // q channel c=k2: head=c>>2, d=c&3
            qb[((b*4 + (k2>>2))*NPix + hw)*4 + (k2&3)] = acc[k2];
    } else if (part == 1){
        #pragma unroll
        for (int k2=0;k2<16;k2++)
            kb[((b*4 + (k2>>2))*NPix + hw)*4 + (k2&3)] = acc[k2];
    } else {
        int cbase = (part-2)*16;
        #pragma unroll
        for (int k2=0;k2<16;k2++){
            int c2 = cbase + k2;    // v channel: head=c2>>3, d=c2&7
            vb[((b*4 + (c2>>3))*NPix + hw)*8 + (c2&7)] = acc[k2];
        }
    }
}

// ---------------- causal attention: 8 lanes/query, two-pass softmax, K/V in LDS ----
__global__ __launch_bounds__(256) void k_attn(const float* __restrict__ qb,
        const float* __restrict__ kb, const float* __restrict__ vb,
        float* __restrict__ ob)
{
    __shared__ float4 kv4[1024*3];               // k: [0..1023], v: [1024 + 2j + half]
    int bi = blockIdx.x;                         // grid 1024 = 8b * 4h * 32 chunks
    int b = bi >> 7, hd = (bi >> 5) & 3, chunk = bi & 31;
    int qbase = chunk * 32;
    int qend  = qbase + 32;                      // keys needed: j < qend
    int t = threadIdx.x;
    int bh = b*4 + hd;
    const float4* ksrc = reinterpret_cast<const float4*>(kb) + bh*NPix;
    const float4* vsrc = reinterpret_cast<const float4*>(vb) + bh*NPix*2;
    for (int idx = t; idx < qend*3; idx += 256){
        if (idx < qend) kv4[idx] = ksrc[idx];
        else            kv4[1024 + (idx - qend)] = vsrc[idx - qend];
    }
    __syncthreads();
    int wv = t >> 6, lane = t & 63;
    int g = lane >> 3, sub = lane & 7;
    int q = qbase + wv*8 + g;
    float4 qv = reinterpret_cast<const float4*>(qb)[bh*NPix + q];
    // pass 1: max
    float m = -1e30f;
    for (int j = sub; j < qend; j += 8){
        float4 kk = kv4[j];
        float s = 0.5f*(qv.x*kk.x + qv.y*kk.y + qv.z*kk.z + qv.w*kk.w);
        if (j <= q) m = fmaxf(m, s);
    }
    #pragma unroll
    for (int off=1; off<8; off<<=1) m = fmaxf(m, __shfl_xor(m, off));
    // pass 2: exp-sum + PV
    float lsum = 0.f;
    float4 acc0 = {0,0,0,0}, acc1 = {0,0,0,0};
    for (int j = sub; j < qend; j += 8){
        float4 kk = kv4[j];
        float s = 0.5f*(qv.x*kk.x + qv.y*kk.y + qv.z*kk.z + qv.w*kk.w);
        float p = (j <= q) ? expf(s - m) : 0.f;
        lsum += p;
        float4 v0 = kv4[1024 + j*2];
        float4 v1 = kv4[1024 + j*2 + 1];
        acc0.x = fmaf(p, v0.x, acc0.x); acc0.y = fmaf(p, v0.y, acc0.y);
        acc0.z = fmaf(p, v0.z, acc0.z); acc0.w = fmaf(p, v0.w, acc0.w);
        acc1.x = fmaf(p, v1.x, acc1.x); acc1.y = fmaf(p, v1.y, acc1.y);
        acc1.z = fmaf(p, v1.z, acc1.z); acc1.w = fmaf(p, v1.w, acc1.w);
    }
    #pragma unroll
    for (int off=1; off<8; off<<=1){
        lsum   += __shfl_xor(lsum, off);
        acc0.x += __shfl_xor(acc0.x, off); acc0.y += __shfl_xor(acc0.y, off);
        acc0.z += __shfl_xor(acc0.z, off); acc0.w += __shfl_xor(acc0.w, off);
        acc1.x += __shfl_xor(acc1.x, off); acc1.y += __shfl_xor(acc1.y, off);
        acc1.z += __shfl_xor(acc1.z, off); acc1.w += __shfl_xor(acc1.w, off);
    }
    if (sub == 0){
        float inv = 1.f / lsum;
        float4 r0 = {acc0.x*inv, acc0.y*inv, acc0.z*inv, acc0.w*inv};
        float4 r1 = {acc1.x*inv, acc1.y*inv, acc1.z*inv, acc1.w*inv};
        float4* od = reinterpret_cast<float4*>(ob) + (bh*NPix + q)*2;
        od[0] = r0; od[1] = r1;
    }
}

// ---------------- epilogue: proj -> outa | outc | outp chain + residual ----
__global__ __launch_bounds__(256) void k_epi(const float* __restrict__ ob,
        const float* __restrict__ conv_raw, float* __restrict__ out,
        const float* __restrict__ pw,  const float* __restrict__ pb,
        const float* __restrict__ cw,  const float* __restrict__ cb2,
        const float* __restrict__ aw,  const float* __restrict__ ab,
        const float* __restrict__ ppw, const float* __restrict__ ppb,
        float* __restrict__ e_out)
{
    __shared__ float s_ov[4][32];
    __shared__ float s_e1[4][64];
    __shared__ float s_ecv[4][64];
    __shared__ float s_g[4][64];
    int t = threadIdx.x;
    int wv = t >> 6, lane = t & 63;              // lane = output channel
    int pix = blockIdx.x*4 + wv;                 // grid 2048
    int b = pix >> 10, hw = pix & 1023;
    if (lane < 32)                               // attn o channel = head*8+d = lane
        s_ov[wv][lane] = ob[(b*4 + (lane>>3))*NPix*8 + hw*8 + (lane&7)];
    s_ecv[wv][lane] = elu_f(conv_raw[(b*64+lane)*NPix + hw]);
    __syncthreads();
    float a0 = pb[lane];
    const float* pwr = pw + lane*32;
    #pragma unroll
    for (int i=0;i<32;i++) a0 = fmaf(pwr[i], s_ov[wv][i], a0);
    s_e1[wv][lane] = elu_f(a0);                  // elu(attn-proj)
    __syncthreads();
    float a1 = ab[lane], c1 = cb2[lane];
    const float* awr = aw + lane*64;
    const float* cwr = cw + lane*64;
    #pragma unroll
    for (int i=0;i<64;i++){
        a1 = fmaf(awr[i], s_e1[wv][i], a1);
        c1 = fmaf(cwr[i], s_ecv[wv][i], c1);
    }
    a1 = elu_f(a1); c1 = elu_f(c1);
    s_g[wv][lane] = elu_f(c1 + a1);
    __syncthreads();
    float bl = ppb[lane];
    const float* pwr2 = ppw + lane*64;
    #pragma unroll
    for (int i=0;i<64;i++) bl = fmaf(pwr2[i], s_g[wv][i], bl);
    bl = elu_f(bl);
    int gi = (b*64+lane)*NPix + hw;
    float on = bl + out[gi];
    out[gi] = on;
    e_out[gi] = elu_f(on);
}

// ---------------- final 1x1: logits = fc_w . elu(out) + fc_b ----
__global__ __launch_bounds__(256) void k_final(const float* __restrict__ out,
        const float* __restrict__ fw, const float* __restrict__ fb,
        float* __restrict__ logits)
{
    int idx = blockIdx.x*256 + threadIdx.x;      // grid 32*256 = 8192
    int b = idx >> 10, hw = idx & 1023;
    float acc = fb[0];
    for (int i=0;i<64;i++)
        acc = fmaf(fw[i], elu_f(out[(b*64+i)*NPix + hw]), acc);
    logits[idx] = acc;
}

extern "C" void kernel_launch(void* const* d_in, const int* in_sizes, int n_in,
                              void* d_out, int out_size, void* d_ws, size_t ws_size,
                              hipStream_t stream)
{
    const float* x      = (const float*)d_in[0];
    const float* stem_w = (const float*)d_in[1];
    const float* stem_b = (const float*)d_in[2];
    const float* bb1_w  = (const float*)d_in[3];
    const float* bb1_b  = (const float*)d_in[4];
    const float* bb2_w  = (const float*)d_in[5];
    const float* bb2_b  = (const float*)d_in[6];
    const float* qkv_w  = (const float*)d_in[7];
    const float* qkv_b  = (const float*)d_in[8];
    const float* proj_w = (const float*)d_in[9];
    const float* proj_b = (const float*)d_in[10];
    const float* outc_w = (const float*)d_in[11];
    const float* outc_b = (const float*)d_in[12];
    const float* outa_w = (const float*)d_in[13];
    const float* outa_b = (const float*)d_in[14];
    const float* outp_w = (const float*)d_in[15];
    const float* outp_b = (const float*)d_in[16];
    const float* fc_w   = (const float*)d_in[17];
    const float* fc_b   = (const float*)d_in[18];
    float* logits = (float*)d_out;

    // workspace layout (floats); total 2,883,584 floats = 11.6 MB
    float* W        = (float*)d_ws;
    float* out_buf  = W;                  // B*64*N
    float* e_conv   = W + 524288;         // elu of current activation
    float* conv_raw = W + 2*524288;
    float* t1e      = W + 3*524288;
    float* qbuf     = W + 4*524288;       // [b][h][n][4]
    float* kbuf     = qbuf + 131072;
    float* vbuf     = kbuf + 131072;      // [b][h][n][8]
    float* obuf     = vbuf + 262144;      // [b][h][n][8]

    k_stem<<<32,256,0,stream>>>(x, stem_w, stem_b, out_buf, e_conv);
    for (int s=0;s<8;s++){
        for (int l=0;l<2;l++){
            int sl = s*2+l;
            k_bbA<<<256,256,0,stream>>>(e_conv, bb1_w + sl*16384, bb1_b + sl*64, t1e);
            const float* xres = (l==0) ? out_buf : conv_raw;
            k_bbB<<<256,256,0,stream>>>(t1e, xres, bb2_w + sl*32768, bb2_b + sl*128,
                                        conv_raw, e_conv);
        }
        k_qkv<<<128,256,0,stream>>>(conv_raw, qkv_w + s*4224, qkv_b + s*64,
                                    qbuf, kbuf, vbuf);
        k_attn<<<1024,256,0,stream>>>(qbuf, kbuf, vbuf, obuf);
        k_epi<<<2048,256,0,stream>>>(obuf, conv_raw, out_buf,
                                     proj_w + s*2048, proj_b + s*64,
                                     outc_w + s*4096, outc_b + s*64,
                                     outa_w + s*4096, outa_b + s*64,
                                     outp_w + s*4096, outp_b + s*64,
                                     e_conv);
    }
    k_final<<<32,256,0,stream>>>(out_buf, fc_w, fc_b, logits);
}

// Round 2
// 2014.119 us; speedup vs baseline: 1.1774x; 1.1774x over previous
//
#include <hip/hip_runtime.h>
#include <math.h>

// PixelSnail forward, fp32. B=8, CH=1, H=W=32 (N=1024), HID=64, S=8, L=2,
// HEAD=4, QK=16 (d=4/head), VD=32 (8/head).

#define NPix 1024

__device__ __forceinline__ float elu_f(float x){ return x > 0.f ? x : __expf(x) - 1.f; }
__device__ __forceinline__ float sig_f(float x){ return 1.f / (1.f + __expf(-x)); }

// ---------------- stem: masked 3x3 conv, 1->64, taps (0,0)(0,1)(0,2)(1,0) ----
// grid 256 = b*32+h, 256 thr: col = t&31, slot = t>>5 (8 outputs each)
__global__ __launch_bounds__(256) void k_stem(const float* __restrict__ x,
        const float* __restrict__ w, const float* __restrict__ bias,
        float* __restrict__ out, float* __restrict__ e_out)
{
    int b = blockIdx.x >> 5, h = blockIdx.x & 31;
    int t = threadIdx.x;
    int col = t & 31, slot = t >> 5;
    int hw = h*32 + col;
    const float* xb = x + b*NPix;
    float x00=0.f, x01=0.f, x02=0.f, x10=0.f;
    if (h > 0){
        if (col > 0)  x00 = xb[hw-33];
        x01 = xb[hw-32];
        if (col < 31) x02 = xb[hw-31];
    }
    if (col > 0) x10 = xb[hw-1];
    #pragma unroll
    for (int k2=0;k2<8;k2++){
        int o = slot*8 + k2;
        const float* wo = w + o*9;               // [o][0][3][3]
        float v = bias[o] + wo[0]*x00 + wo[1]*x01 + wo[2]*x02 + wo[3]*x10;
        out[(b*64+o)*NPix + hw] = v;
        e_out[(b*64+o)*NPix + hw] = elu_f(v);
    }
}

// ---------------- basic-block conv1: elu'd input, 2x2 causal conv 64->64, out = elu ----
// grid 256 = b*32+h, 512 thr: col = t&31, slot = t>>5 (16 slots x 4 outputs)
__global__ __launch_bounds__(512) void k_bbA(const float* __restrict__ ein,
        const float* __restrict__ w, const float* __restrict__ bias,
        float* __restrict__ t1e)
{
    __shared__ float eld[2*64*33];               // [r(h-1,h)][i][col -1..31]
    int b = blockIdx.x >> 5;
    int h = blockIdx.x & 31;
    int t = threadIdx.x;
    for (int idx = t; idx < 2*64*33; idx += 512){
        int cpos = idx % 33;
        int ri = idx / 33;
        int r = ri >> 6, i = ri & 63;
        int row = h - 1 + r, col = cpos - 1;
        float v = 0.f;
        if (row >= 0 && col >= 0) v = ein[(b*64+i)*NPix + row*32 + col];
        eld[idx] = v;
    }
    __syncthreads();
    int col  = t & 31;
    int slot = t >> 5;
    float acc[4];
    #pragma unroll
    for (int k2=0;k2<4;k2++) acc[k2] = bias[slot*4+k2];
    const float* wbase = w + slot*4*64*4;        // [o][i][2][2]
    for (int i=0;i<64;i++){
        float e00 = eld[i*33 + col];
        float e01 = eld[i*33 + col + 1];
        float e10 = eld[(64+i)*33 + col];
        float e11 = eld[(64+i)*33 + col + 1];
        #pragma unroll
        for (int k2=0;k2<4;k2++){
            float4 wv = *reinterpret_cast<const float4*>(wbase + (k2*64 + i)*4);
            acc[k2] = fmaf(wv.x, e00, acc[k2]);
            acc[k2] = fmaf(wv.y, e01, acc[k2]);
            acc[k2] = fmaf(wv.z, e10, acc[k2]);
            acc[k2] = fmaf(wv.w, e11, acc[k2]);
        }
    }
    int base = b*64*NPix + h*32 + col;
    #pragma unroll
    for (int k2=0;k2<4;k2++)
        t1e[base + (slot*4+k2)*NPix] = elu_f(acc[k2]);
}

// ---------------- basic-block conv2 + gate: 2x2 conv 64->128, x + x1*sig(x2) ----
// grid 256, 512 thr: 16 slots x 8 outputs
__global__ __launch_bounds__(512) void k_bbB(const float* __restrict__ ein,
        const float* __restrict__ xres,
        const float* __restrict__ w, const float* __restrict__ bias,
        float* __restrict__ conv_out, float* __restrict__ e_out)
{
    __shared__ float eld[2*64*33];
    __shared__ float obuf[128*32];
    int b = blockIdx.x >> 5;
    int h = blockIdx.x & 31;
    int t = threadIdx.x;
    for (int idx = t; idx < 2*64*33; idx += 512){
        int cpos = idx % 33;
        int ri = idx / 33;
        int r = ri >> 6, i = ri & 63;
        int row = h - 1 + r, col = cpos - 1;
        float v = 0.f;
        if (row >= 0 && col >= 0) v = ein[(b*64+i)*NPix + row*32 + col];
        eld[idx] = v;
    }
    __syncthreads();
    int col  = t & 31;
    int slot = t >> 5;
    float acc[8];
    #pragma unroll
    for (int k2=0;k2<8;k2++) acc[k2] = bias[slot*8+k2];
    const float* wbase = w + slot*8*64*4;        // [128][64][2][2]
    for (int i=0;i<64;i++){
        float e00 = eld[i*33 + col];
        float e01 = eld[i*33 + col + 1];
        float e10 = eld[(64+i)*33 + col];
        float e11 = eld[(64+i)*33 + col + 1];
        #pragma unroll
        for (int k2=0;k2<8;k2++){
            float4 wv = *reinterpret_cast<const float4*>(wbase + (k2*64 + i)*4);
            acc[k2] = fmaf(wv.x, e00, acc[k2]);
            acc[k2] = fmaf(wv.y, e01, acc[k2]);
            acc[k2] = fmaf(wv.z, e10, acc[k2]);
            acc[k2] = fmaf(wv.w, e11, acc[k2]);
        }
    }
    #pragma unroll
    for (int k2=0;k2<8;k2++) obuf[(slot*8+k2)*32 + col] = acc[k2];
    __syncthreads();
    for (int idx = t; idx < 64*32; idx += 512){
        int o = idx >> 5, c2 = idx & 31;
        float x1 = obuf[o*32 + c2], x2 = obuf[(o+64)*32 + c2];
        int gi = (b*64+o)*NPix + h*32 + c2;
        float v = fmaf(x1, sig_f(x2), xres[gi]);
        conv_out[gi] = v;
        e_out[gi] = elu_f(v);
    }
}

// ---------------- qkv 1x1 conv: (conv_raw 64ch + pos 2ch) -> q/k/v head layouts ----
// grid 512 = b*64 + tile(16px), 256 thr: px = t&15, part = t>>4 (16 parts x 4 ch)
__global__ __launch_bounds__(256) void k_qkv(const float* __restrict__ conv,
        const float* __restrict__ w, const float* __restrict__ bias,
        float* __restrict__ qb, float* __restrict__ kb, float* __restrict__ vb)
{
    __shared__ float cl[64*16];                  // [i][px]
    int b = blockIdx.x >> 6;
    int hwbase = (blockIdx.x & 63) * 16;
    int t = threadIdx.x;
    for (int idx = t; idx < 64*16; idx += 256){
        int i = idx >> 4, p = idx & 15;
        cl[idx] = conv[(b*64+i)*NPix + hwbase + p];
    }
    __syncthreads();
    int px = t & 15, part = t >> 4;
    int hw = hwbase + px;
    float py  = (float)(hw >> 5) * (1.f/32.f) - 0.5f;
    float pxc = (float)(hw & 31) * (1.f/32.f) - 0.5f;
    int c0 = part*4;
    float acc[4];
    #pragma unroll
    for (int k2=0;k2<4;k2++){
        const float* wr = w + (c0+k2)*66;
        acc[k2] = bias[c0+k2] + wr[64]*py + wr[65]*pxc;
    }
    for (int i=0;i<64;i++){
        float e = cl[i*16 + px];
        #pragma unroll
        for (int k2=0;k2<4;k2++)
            acc[k2] = fmaf(w[(c0+k2)*66 + i], e, acc[k2]);
    }
    if (c0 < 16){
        #pragma unroll
        for (int k2=0;k2<4;k2++){
            int c = c0 + k2;                     // q: head=c>>2, d=c&3
            qb[((b*4 + (c>>2))*NPix + hw)*4 + (c&3)] = acc[k2];
        }
    } else if (c0 < 32){
        #pragma unroll
        for (int k2=0;k2<4;k2++){
            int c = c0 + k2 - 16;
            kb[((b*4 + (c>>2))*NPix + hw)*4 + (c&3)] = acc[k2];
        }
    } else {
        #pragma unroll
        for (int k2=0;k2<4;k2++){
            int c2 = c0 + k2 - 32;               // v: head=c2>>3, d=c2&7
            vb[((b*4 + (c2>>3))*NPix + hw)*8 + (c2&7)] = acc[k2];
        }
    }
}

// ---------------- causal attention, balanced stride-32 queries, no LDS ----
// grid 1024 = bh*32 + r, 256 thr: 8 lanes/query, q = (wv*8+g)*32 + r
__global__ __launch_bounds__(256) void k_attn(const float* __restrict__ qb,
        const float* __restrict__ kb, const float* __restrict__ vb,
        float* __restrict__ ob)
{
    int bi = blockIdx.x;
    int bh = bi >> 5, r = bi & 31;
    int t = threadIdx.x;
    int wv = t >> 6, lane = t & 63;
    int g = lane >> 3, sub = lane & 7;
    int q = ((wv*8 + g) << 5) + r;
    const float4* k4 = reinterpret_cast<const float4*>(kb) + bh*NPix;
    const float4* v4 = reinterpret_cast<const float4*>(vb) + bh*NPix*2;
    float4 qv = reinterpret_cast<const float4*>(qb)[bh*NPix + q];
    // pass 1: max over j <= q
    float m = -1e30f;
    for (int j = sub; j <= q; j += 8){
        float4 kk = k4[j];
        float s = 0.5f*(qv.x*kk.x + qv.y*kk.y + qv.z*kk.z + qv.w*kk.w);
        m = fmaxf(m, s);
    }
    #pragma unroll
    for (int off=1; off<8; off<<=1) m = fmaxf(m, __shfl_xor(m, off));
    // pass 2: exp-sum + PV
    float lsum = 0.f;
    float4 acc0 = {0,0,0,0}, acc1 = {0,0,0,0};
    for (int j = sub; j <= q; j += 8){
        float4 kk = k4[j];
        float s = 0.5f*(qv.x*kk.x + qv.y*kk.y + qv.z*kk.z + qv.w*kk.w);
        float p = __expf(s - m);
        lsum += p;
        float4 v0 = v4[2*j];
        float4 v1 = v4[2*j + 1];
        acc0.x = fmaf(p, v0.x, acc0.x); acc0.y = fmaf(p, v0.y, acc0.y);
        acc0.z = fmaf(p, v0.z, acc0.z); acc0.w = fmaf(p, v0.w, acc0.w);
        acc1.x = fmaf(p, v1.x, acc1.x); acc1.y = fmaf(p, v1.y, acc1.y);
        acc1.z = fmaf(p, v1.z, acc1.z); acc1.w = fmaf(p, v1.w, acc1.w);
    }
    #pragma unroll
    for (int off=1; off<8; off<<=1){
        lsum   += __shfl_xor(lsum, off);
        acc0.x += __shfl_xor(acc0.x, off); acc0.y += __shfl_xor(acc0.y, off);
        acc0.z += __shfl_xor(acc0.z, off); acc0.w += __shfl_xor(acc0.w, off);
        acc1.x += __shfl_xor(acc1.x, off); acc1.y += __shfl_xor(acc1.y, off);
        acc1.z += __shfl_xor(acc1.z, off); acc1.w += __shfl_xor(acc1.w, off);
    }
    if (sub == 0){
        float inv = 1.f / lsum;
        float4 r0 = {acc0.x*inv, acc0.y*inv, acc0.z*inv, acc0.w*inv};
        float4 r1 = {acc1.x*inv, acc1.y*inv, acc1.z*inv, acc1.w*inv};
        float4* od = reinterpret_cast<float4*>(ob) + (bh*NPix + q)*2;
        od[0] = r0; od[1] = r1;
    }
}

// ---------------- epilogue: proj -> outa | outc | outp chain + residual ----
__global__ __launch_bounds__(256) void k_epi(const float* __restrict__ ob,
        const float* __restrict__ conv_raw, float* __restrict__ out,
        const float* __restrict__ pw,  const float* __restrict__ pb,
        const float* __restrict__ cw,  const float* __restrict__ cb2,
        const float* __restrict__ aw,  const float* __restrict__ ab,
        const float* __restrict__ ppw, const float* __restrict__ ppb,
        float* __restrict__ e_out)
{
    __shared__ float s_ov[4][32];
    __shared__ float s_e1[4][64];
    __shared__ float s_ecv[4][64];
    __shared__ float s_g[4][64];
    int t = threadIdx.x;
    int wv = t >> 6, lane = t & 63;              // lane = output channel
    int pix = blockIdx.x*4 + wv;                 // grid 2048
    int b = pix >> 10, hw = pix & 1023;
    if (lane < 32)                               // attn o channel = head*8+d = lane
        s_ov[wv][lane] = ob[(b*4 + (lane>>3))*NPix*8 + hw*8 + (lane&7)];
    s_ecv[wv][lane] = elu_f(conv_raw[(b*64+lane)*NPix + hw]);
    __syncthreads();
    float a0 = pb[lane];
    const float* pwr = pw + lane*32;
    #pragma unroll
    for (int i=0;i<32;i++) a0 = fmaf(pwr[i], s_ov[wv][i], a0);
    s_e1[wv][lane] = elu_f(a0);                  // elu(attn-proj)
    __syncthreads();
    float a1 = ab[lane], c1 = cb2[lane];
    const float* awr = aw + lane*64;
    const float* cwr = cw + lane*64;
    #pragma unroll
    for (int i=0;i<64;i++){
        a1 = fmaf(awr[i], s_e1[wv][i], a1);
        c1 = fmaf(cwr[i], s_ecv[wv][i], c1);
    }
    a1 = elu_f(a1); c1 = elu_f(c1);
    s_g[wv][lane] = elu_f(c1 + a1);
    __syncthreads();
    float bl = ppb[lane];
    const float* pwr2 = ppw + lane*64;
    #pragma unroll
    for (int i=0;i<64;i++) bl = fmaf(pwr2[i], s_g[wv][i], bl);
    bl = elu_f(bl);
    int gi = (b*64+lane)*NPix + hw;
    float on = bl + out[gi];
    out[gi] = on;
    e_out[gi] = elu_f(on);
}

// ---------------- final 1x1: logits = fc_w . elu(out) + fc_b ----
// grid 256x256: 8 lanes per pixel, shuffle-reduce over channels
__global__ __launch_bounds__(256) void k_final(const float* __restrict__ out,
        const float* __restrict__ fw, const float* __restrict__ fb,
        float* __restrict__ logits)
{
    int idx = blockIdx.x*256 + threadIdx.x;      // 65536
    int pix = idx >> 3, sub = idx & 7;
    int b = pix >> 10, hw = pix & 1023;
    const float* obp = out + b*64*NPix + hw;
    float acc = 0.f;
    #pragma unroll
    for (int k=0;k<8;k++){
        int i = sub*8 + k;
        acc = fmaf(fw[i], elu_f(obp[i*NPix]), acc);
    }
    #pragma unroll
    for (int off=1; off<8; off<<=1) acc += __shfl_xor(acc, off);
    if (sub == 0) logits[pix] = acc + fb[0];
}

extern "C" void kernel_launch(void* const* d_in, const int* in_sizes, int n_in,
                              void* d_out, int out_size, void* d_ws, size_t ws_size,
                              hipStream_t stream)
{
    const float* x      = (const float*)d_in[0];
    const float* stem_w = (const float*)d_in[1];
    const float* stem_b = (const float*)d_in[2];
    const float* bb1_w  = (const float*)d_in[3];
    const float* bb1_b  = (const float*)d_in[4];
    const float* bb2_w  = (const float*)d_in[5];
    const float* bb2_b  = (const float*)d_in[6];
    const float* qkv_w  = (const float*)d_in[7];
    const float* qkv_b  = (const float*)d_in[8];
    const float* proj_w = (const float*)d_in[9];
    const float* proj_b = (const float*)d_in[10];
    const float* outc_w = (const float*)d_in[11];
    const float* outc_b = (const float*)d_in[12];
    const float* outa_w = (const float*)d_in[13];
    const float* outa_b = (const float*)d_in[14];
    const float* outp_w = (const float*)d_in[15];
    const float* outp_b = (const float*)d_in[16];
    const float* fc_w   = (const float*)d_in[17];
    const float* fc_b   = (const float*)d_in[18];
    float* logits = (float*)d_out;

    float* W        = (float*)d_ws;
    float* out_buf  = W;                  // B*64*N
    float* e_conv   = W + 524288;
    float* conv_raw = W + 2*524288;
    float* t1e      = W + 3*524288;
    float* qbuf     = W + 4*524288;       // [b][h][n][4]
    float* kbuf     = qbuf + 131072;
    float* vbuf     = kbuf + 131072;      // [b][h][n][8]
    float* obuf     = vbuf + 262144;      // [b][h][n][8]

    k_stem<<<256,256,0,stream>>>(x, stem_w, stem_b, out_buf, e_conv);
    for (int s=0;s<8;s++){
        for (int l=0;l<2;l++){
            int sl = s*2+l;
            k_bbA<<<256,512,0,stream>>>(e_conv, bb1_w + sl*16384, bb1_b + sl*64, t1e);
            const float* xres = (l==0) ? out_buf : conv_raw;
            k_bbB<<<256,512,0,stream>>>(t1e, xres, bb2_w + sl*32768, bb2_b + sl*128,
                                        conv_raw, e_conv);
        }
        k_qkv<<<512,256,0,stream>>>(conv_raw, qkv_w + s*4224, qkv_b + s*64,
                                    qbuf, kbuf, vbuf);
        k_attn<<<1024,256,0,stream>>>(qbuf, kbuf, vbuf, obuf);
        k_epi<<<2048,256,0,stream>>>(obuf, conv_raw, out_buf,
                                     proj_w + s*2048, proj_b + s*64,
                                     outc_w + s*4096, outc_b + s*64,
                                     outa_w + s*4096, outa_b + s*64,
                                     outp_w + s*4096, outp_b + s*64,
                                     e_conv);
    }
    k_final<<<256,256,0,stream>>>(out_buf, fc_w, fc_b, logits);
}

// Round 3
// 1661.431 us; speedup vs baseline: 1.4273x; 1.2123x over previous
//
#include <hip/hip_runtime.h>
#include <math.h>

// PixelSnail forward, fp32. B=8, CH=1, H=W=32 (N=1024), HID=64, S=8, L=2,
// HEAD=4, QK=16 (d=4/head), VD=32 (8/head).

#define NPix 1024

__device__ __forceinline__ float elu_f(float x){ return x > 0.f ? x : __expf(x) - 1.f; }
__device__ __forceinline__ float sig_f(float x){ return 1.f / (1.f + __expf(-x)); }

// ---------------- stem: masked 3x3 conv, 1->64, taps (0,0)(0,1)(0,2)(1,0) ----
__global__ __launch_bounds__(256) void k_stem(const float* __restrict__ x,
        const float* __restrict__ w, const float* __restrict__ bias,
        float* __restrict__ out, float* __restrict__ e_out)
{
    int b = blockIdx.x >> 5, h = blockIdx.x & 31;
    int t = threadIdx.x;
    int col = t & 31, slot = t >> 5;
    int hw = h*32 + col;
    const float* xb = x + b*NPix;
    float x00=0.f, x01=0.f, x02=0.f, x10=0.f;
    if (h > 0){
        if (col > 0)  x00 = xb[hw-33];
        x01 = xb[hw-32];
        if (col < 31) x02 = xb[hw-31];
    }
    if (col > 0) x10 = xb[hw-1];
    #pragma unroll
    for (int k2=0;k2<8;k2++){
        int o = slot*8 + k2;
        const float* wo = w + o*9;               // [o][0][3][3]
        float v = bias[o] + wo[0]*x00 + wo[1]*x01 + wo[2]*x02 + wo[3]*x10;
        out[(b*64+o)*NPix + hw] = v;
        e_out[(b*64+o)*NPix + hw] = elu_f(v);
    }
}

// ---------------- basic-block conv1: elu'd input, 2x2 causal conv 64->64, out = elu ----
// grid 256 = b*32+h, 512 thr: col = t&31, slot = t>>5 (16 slots x 4 outputs)
__global__ __launch_bounds__(512) void k_bbA(const float* __restrict__ ein,
        const float* __restrict__ w, const float* __restrict__ bias,
        float* __restrict__ t1e)
{
    __shared__ float eld[2*64*33];               // [r(h-1,h)][i][col -1..31]
    int b = blockIdx.x >> 5;
    int h = blockIdx.x & 31;
    int t = threadIdx.x;
    for (int idx = t; idx < 2*64*33; idx += 512){
        int cpos = idx % 33;
        int ri = idx / 33;
        int r = ri >> 6, i = ri & 63;
        int row = h - 1 + r, col = cpos - 1;
        float v = 0.f;
        if (row >= 0 && col >= 0) v = ein[(b*64+i)*NPix + row*32 + col];
        eld[idx] = v;
    }
    __syncthreads();
    int col  = t & 31;
    int slot = t >> 5;
    float acc[4];
    #pragma unroll
    for (int k2=0;k2<4;k2++) acc[k2] = bias[slot*4+k2];
    const float* wbase = w + slot*4*64*4;        // [o][i][2][2]
    #pragma unroll 2
    for (int i=0;i<64;i++){
        float e00 = eld[i*33 + col];
        float e01 = eld[i*33 + col + 1];
        float e10 = eld[(64+i)*33 + col];
        float e11 = eld[(64+i)*33 + col + 1];
        #pragma unroll
        for (int k2=0;k2<4;k2++){
            float4 wv = *reinterpret_cast<const float4*>(wbase + (k2*64 + i)*4);
            acc[k2] = fmaf(wv.x, e00, acc[k2]);
            acc[k2] = fmaf(wv.y, e01, acc[k2]);
            acc[k2] = fmaf(wv.z, e10, acc[k2]);
            acc[k2] = fmaf(wv.w, e11, acc[k2]);
        }
    }
    int base = b*64*NPix + h*32 + col;
    #pragma unroll
    for (int k2=0;k2<4;k2++)
        t1e[base + (slot*4+k2)*NPix] = elu_f(acc[k2]);
}

// ---------------- basic-block conv2 + gate: 2x2 conv 64->128, x + x1*sig(x2) ----
// grid 256, 512 thr: 16 slots x 8 outputs
__global__ __launch_bounds__(512) void k_bbB(const float* __restrict__ ein,
        const float* __restrict__ xres,
        const float* __restrict__ w, const float* __restrict__ bias,
        float* __restrict__ conv_out, float* __restrict__ e_out)
{
    __shared__ float eld[2*64*33];
    __shared__ float obuf[128*32];
    int b = blockIdx.x >> 5;
    int h = blockIdx.x & 31;
    int t = threadIdx.x;
    for (int idx = t; idx < 2*64*33; idx += 512){
        int cpos = idx % 33;
        int ri = idx / 33;
        int r = ri >> 6, i = ri & 63;
        int row = h - 1 + r, col = cpos - 1;
        float v = 0.f;
        if (row >= 0 && col >= 0) v = ein[(b*64+i)*NPix + row*32 + col];
        eld[idx] = v;
    }
    __syncthreads();
    int col  = t & 31;
    int slot = t >> 5;
    float acc[8];
    #pragma unroll
    for (int k2=0;k2<8;k2++) acc[k2] = bias[slot*8+k2];
    const float* wbase = w + slot*8*64*4;        // [128][64][2][2]
    #pragma unroll 2
    for (int i=0;i<64;i++){
        float e00 = eld[i*33 + col];
        float e01 = eld[i*33 + col + 1];
        float e10 = eld[(64+i)*33 + col];
        float e11 = eld[(64+i)*33 + col + 1];
        #pragma unroll
        for (int k2=0;k2<8;k2++){
            float4 wv = *reinterpret_cast<const float4*>(wbase + (k2*64 + i)*4);
            acc[k2] = fmaf(wv.x, e00, acc[k2]);
            acc[k2] = fmaf(wv.y, e01, acc[k2]);
            acc[k2] = fmaf(wv.z, e10, acc[k2]);
            acc[k2] = fmaf(wv.w, e11, acc[k2]);
        }
    }
    #pragma unroll
    for (int k2=0;k2<8;k2++) obuf[(slot*8+k2)*32 + col] = acc[k2];
    __syncthreads();
    for (int idx = t; idx < 64*32; idx += 512){
        int o = idx >> 5, c2 = idx & 31;
        float x1 = obuf[o*32 + c2], x2 = obuf[(o+64)*32 + c2];
        int gi = (b*64+o)*NPix + h*32 + c2;
        float v = fmaf(x1, sig_f(x2), xres[gi]);
        conv_out[gi] = v;
        e_out[gi] = elu_f(v);
    }
}

// ---------------- qkv 1x1 conv: (conv_raw 64ch + pos 2ch) -> q/k/v head layouts ----
// grid 512 = b*64 + tile(16px), 256 thr: px = t&15, part = t>>4 (16 parts x 4 ch)
__global__ __launch_bounds__(256) void k_qkv(const float* __restrict__ conv,
        const float* __restrict__ w, const float* __restrict__ bias,
        float* __restrict__ qb, float* __restrict__ kb, float* __restrict__ vb)
{
    __shared__ float cl[64*16];                  // [i][px]
    int b = blockIdx.x >> 6;
    int hwbase = (blockIdx.x & 63) * 16;
    int t = threadIdx.x;
    for (int idx = t; idx < 64*16; idx += 256){
        int i = idx >> 4, p = idx & 15;
        cl[idx] = conv[(b*64+i)*NPix + hwbase + p];
    }
    __syncthreads();
    int px = t & 15, part = t >> 4;
    int hw = hwbase + px;
    float py  = (float)(hw >> 5) * (1.f/32.f) - 0.5f;
    float pxc = (float)(hw & 31) * (1.f/32.f) - 0.5f;
    int c0 = part*4;
    float acc[4];
    #pragma unroll
    for (int k2=0;k2<4;k2++){
        const float* wr = w + (c0+k2)*66;
        acc[k2] = bias[c0+k2] + wr[64]*py + wr[65]*pxc;
    }
    #pragma unroll 2
    for (int i=0;i<64;i++){
        float e = cl[i*16 + px];
        #pragma unroll
        for (int k2=0;k2<4;k2++)
            acc[k2] = fmaf(w[(c0+k2)*66 + i], e, acc[k2]);
    }
    if (c0 < 16){
        #pragma unroll
        for (int k2=0;k2<4;k2++){
            int c = c0 + k2;                     // q: head=c>>2, d=c&3
            qb[((b*4 + (c>>2))*NPix + hw)*4 + (c&3)] = acc[k2];
        }
    } else if (c0 < 32){
        #pragma unroll
        for (int k2=0;k2<4;k2++){
            int c = c0 + k2 - 16;
            kb[((b*4 + (c>>2))*NPix + hw)*4 + (c&3)] = acc[k2];
        }
    } else {
        #pragma unroll
        for (int k2=0;k2<4;k2++){
            int c2 = c0 + k2 - 32;               // v: head=c2>>3, d=c2&7
            vb[((b*4 + (c2>>3))*NPix + hw)*8 + (c2&7)] = acc[k2];
        }
    }
}

// ---------------- causal attention, balanced stride-32 queries, no LDS ----
// grid 1024 = bh*32 + r, 256 thr: 8 lanes/query, q = (wv*8+g)*32 + r
__global__ __launch_bounds__(256) void k_attn(const float* __restrict__ qb,
        const float* __restrict__ kb, const float* __restrict__ vb,
        float* __restrict__ ob)
{
    int bi = blockIdx.x;
    int bh = bi >> 5, r = bi & 31;
    int t = threadIdx.x;
    int wv = t >> 6, lane = t & 63;
    int g = lane >> 3, sub = lane & 7;
    int q = ((wv*8 + g) << 5) + r;
    const float4* k4 = reinterpret_cast<const float4*>(kb) + bh*NPix;
    const float4* v4 = reinterpret_cast<const float4*>(vb) + bh*NPix*2;
    float4 qv = reinterpret_cast<const float4*>(qb)[bh*NPix + q];
    // pass 1: max over j <= q
    float m = -1e30f;
    for (int j = sub; j <= q; j += 8){
        float4 kk = k4[j];
        float s = 0.5f*(qv.x*kk.x + qv.y*kk.y + qv.z*kk.z + qv.w*kk.w);
        m = fmaxf(m, s);
    }
    #pragma unroll
    for (int off=1; off<8; off<<=1) m = fmaxf(m, __shfl_xor(m, off));
    // pass 2: exp-sum + PV
    float lsum = 0.f;
    float4 acc0 = {0,0,0,0}, acc1 = {0,0,0,0};
    for (int j = sub; j <= q; j += 8){
        float4 kk = k4[j];
        float s = 0.5f*(qv.x*kk.x + qv.y*kk.y + qv.z*kk.z + qv.w*kk.w);
        float p = __expf(s - m);
        lsum += p;
        float4 v0 = v4[2*j];
        float4 v1 = v4[2*j + 1];
        acc0.x = fmaf(p, v0.x, acc0.x); acc0.y = fmaf(p, v0.y, acc0.y);
        acc0.z = fmaf(p, v0.z, acc0.z); acc0.w = fmaf(p, v0.w, acc0.w);
        acc1.x = fmaf(p, v1.x, acc1.x); acc1.y = fmaf(p, v1.y, acc1.y);
        acc1.z = fmaf(p, v1.z, acc1.z); acc1.w = fmaf(p, v1.w, acc1.w);
    }
    #pragma unroll
    for (int off=1; off<8; off<<=1){
        lsum   += __shfl_xor(lsum, off);
        acc0.x += __shfl_xor(acc0.x, off); acc0.y += __shfl_xor(acc0.y, off);
        acc0.z += __shfl_xor(acc0.z, off); acc0.w += __shfl_xor(acc0.w, off);
        acc1.x += __shfl_xor(acc1.x, off); acc1.y += __shfl_xor(acc1.y, off);
        acc1.z += __shfl_xor(acc1.z, off); acc1.w += __shfl_xor(acc1.w, off);
    }
    if (sub == 0){
        float inv = 1.f / lsum;
        float4 r0 = {acc0.x*inv, acc0.y*inv, acc0.z*inv, acc0.w*inv};
        float4 r1 = {acc1.x*inv, acc1.y*inv, acc1.z*inv, acc1.w*inv};
        float4* od = reinterpret_cast<float4*>(ob) + (bh*NPix + q)*2;
        od[0] = r0; od[1] = r1;
    }
}

// ---------------- epilogue as tiled GEMM over 32-pixel tiles ----
// grid 256 = b*32 + tile, 256 thr: px = t&31, g = t>>5 (8 groups x 8 outputs)
// chain: e1 = elu(proj.ov); a1 = elu(outa.e1); c1 = elu(outc.ecv);
//        g2 = elu(a1+c1); blk = elu(outp.g2); out += blk; e_out = elu(out)
__global__ __launch_bounds__(256) void k_epi(const float* __restrict__ ob,
        const float* __restrict__ conv_raw, float* __restrict__ out,
        const float* __restrict__ pw,  const float* __restrict__ pb,
        const float* __restrict__ cw,  const float* __restrict__ cb2,
        const float* __restrict__ aw,  const float* __restrict__ ab,
        const float* __restrict__ ppw, const float* __restrict__ ppb,
        float* __restrict__ e_out)
{
    __shared__ float s_x[64][33];    // elu(conv_raw)
    __shared__ float s_ov[32][33];   // attention output (pre-proj), c = head*8+d
    __shared__ float s_e1[64][33];   // elu(proj)
    __shared__ float s_g[64][33];    // elu(a1+c1)
    int b = blockIdx.x >> 5;
    int hw0 = (blockIdx.x & 31) * 32;
    int t = threadIdx.x;
    for (int idx = t; idx < 64*32; idx += 256){
        int i = idx >> 5, px = idx & 31;
        s_x[i][px] = elu_f(conv_raw[(b*64+i)*NPix + hw0 + px]);
    }
    for (int idx = t; idx < 32*32; idx += 256){
        int c = idx >> 5, px = idx & 31;
        s_ov[c][px] = ob[(b*4 + (c>>3))*NPix*8 + (hw0+px)*8 + (c&7)];
    }
    __syncthreads();
    int px = t & 31, g = t >> 5;
    int o0 = g*8;
    // --- proj: 64x32 ---
    float acc[8];
    #pragma unroll
    for (int k=0;k<8;k++) acc[k] = pb[o0+k];
    #pragma unroll
    for (int i4=0;i4<8;i4++){
        float v0 = s_ov[i4*4+0][px], v1 = s_ov[i4*4+1][px];
        float v2 = s_ov[i4*4+2][px], v3 = s_ov[i4*4+3][px];
        #pragma unroll
        for (int k=0;k<8;k++){
            float4 wv = *reinterpret_cast<const float4*>(pw + (o0+k)*32 + i4*4);
            acc[k] = fmaf(wv.x, v0, acc[k]); acc[k] = fmaf(wv.y, v1, acc[k]);
            acc[k] = fmaf(wv.z, v2, acc[k]); acc[k] = fmaf(wv.w, v3, acc[k]);
        }
    }
    #pragma unroll
    for (int k=0;k<8;k++) s_e1[o0+k][px] = elu_f(acc[k]);
    __syncthreads();
    // --- outa(e1) and outc(ecv): 64x64 each ---
    float aa[8], cc[8];
    #pragma unroll
    for (int k=0;k<8;k++){ aa[k] = ab[o0+k]; cc[k] = cb2[o0+k]; }
    #pragma unroll
    for (int i4=0;i4<16;i4++){
        float e0 = s_e1[i4*4+0][px], e1 = s_e1[i4*4+1][px];
        float e2 = s_e1[i4*4+2][px], e3 = s_e1[i4*4+3][px];
        float x0 = s_x[i4*4+0][px],  x1 = s_x[i4*4+1][px];
        float x2 = s_x[i4*4+2][px],  x3 = s_x[i4*4+3][px];
        #pragma unroll
        for (int k=0;k<8;k++){
            float4 wa = *reinterpret_cast<const float4*>(aw + (o0+k)*64 + i4*4);
            float4 wc = *reinterpret_cast<const float4*>(cw + (o0+k)*64 + i4*4);
            aa[k] = fmaf(wa.x, e0, aa[k]); aa[k] = fmaf(wa.y, e1, aa[k]);
            aa[k] = fmaf(wa.z, e2, aa[k]); aa[k] = fmaf(wa.w, e3, aa[k]);
            cc[k] = fmaf(wc.x, x0, cc[k]); cc[k] = fmaf(wc.y, x1, cc[k]);
            cc[k] = fmaf(wc.z, x2, cc[k]); cc[k] = fmaf(wc.w, x3, cc[k]);
        }
    }
    #pragma unroll
    for (int k=0;k<8;k++) s_g[o0+k][px] = elu_f(elu_f(aa[k]) + elu_f(cc[k]));
    __syncthreads();
    // --- outp: 64x64, residual, final elu ---
    float bl[8];
    #pragma unroll
    for (int k=0;k<8;k++) bl[k] = ppb[o0+k];
    #pragma unroll
    for (int i4=0;i4<16;i4++){
        float g0 = s_g[i4*4+0][px], g1 = s_g[i4*4+1][px];
        float g2 = s_g[i4*4+2][px], g3 = s_g[i4*4+3][px];
        #pragma unroll
        for (int k=0;k<8;k++){
            float4 wv = *reinterpret_cast<const float4*>(ppw + (o0+k)*64 + i4*4);
            bl[k] = fmaf(wv.x, g0, bl[k]); bl[k] = fmaf(wv.y, g1, bl[k]);
            bl[k] = fmaf(wv.z, g2, bl[k]); bl[k] = fmaf(wv.w, g3, bl[k]);
        }
    }
    #pragma unroll
    for (int k=0;k<8;k++){
        int gi = (b*64 + o0 + k)*NPix + hw0 + px;
        float on = elu_f(bl[k]) + out[gi];
        out[gi] = on;
        e_out[gi] = elu_f(on);
    }
}

// ---------------- final 1x1: logits = fc_w . elu(out) + fc_b ----
__global__ __launch_bounds__(256) void k_final(const float* __restrict__ out,
        const float* __restrict__ fw, const float* __restrict__ fb,
        float* __restrict__ logits)
{
    int idx = blockIdx.x*256 + threadIdx.x;      // 65536
    int pix = idx >> 3, sub = idx & 7;
    int b = pix >> 10, hw = pix & 1023;
    const float* obp = out + b*64*NPix + hw;
    float acc = 0.f;
    #pragma unroll
    for (int k=0;k<8;k++){
        int i = sub*8 + k;
        acc = fmaf(fw[i], elu_f(obp[i*NPix]), acc);
    }
    #pragma unroll
    for (int off=1; off<8; off<<=1) acc += __shfl_xor(acc, off);
    if (sub == 0) logits[pix] = acc + fb[0];
}

extern "C" void kernel_launch(void* const* d_in, const int* in_sizes, int n_in,
                              void* d_out, int out_size, void* d_ws, size_t ws_size,
                              hipStream_t stream)
{
    const float* x      = (const float*)d_in[0];
    const float* stem_w = (const float*)d_in[1];
    const float* stem_b = (const float*)d_in[2];
    const float* bb1_w  = (const float*)d_in[3];
    const float* bb1_b  = (const float*)d_in[4];
    const float* bb2_w  = (const float*)d_in[5];
    const float* bb2_b  = (const float*)d_in[6];
    const float* qkv_w  = (const float*)d_in[7];
    const float* qkv_b  = (const float*)d_in[8];
    const float* proj_w = (const float*)d_in[9];
    const float* proj_b = (const float*)d_in[10];
    const float* outc_w = (const float*)d_in[11];
    const float* outc_b = (const float*)d_in[12];
    const float* outa_w = (const float*)d_in[13];
    const float* outa_b = (const float*)d_in[14];
    const float* outp_w = (const float*)d_in[15];
    const float* outp_b = (const float*)d_in[16];
    const float* fc_w   = (const float*)d_in[17];
    const float* fc_b   = (const float*)d_in[18];
    float* logits = (float*)d_out;

    float* W        = (float*)d_ws;
    float* out_buf  = W;                  // B*64*N
    float* e_conv   = W + 524288;
    float* conv_raw = W + 2*524288;
    float* t1e      = W + 3*524288;
    float* qbuf     = W + 4*524288;       // [b][h][n][4]
    float* kbuf     = qbuf + 131072;
    float* vbuf     = kbuf + 131072;      // [b][h][n][8]
    float* obuf     = vbuf + 262144;      // [b][h][n][8]

    k_stem<<<256,256,0,stream>>>(x, stem_w, stem_b, out_buf, e_conv);
    for (int s=0;s<8;s++){
        for (int l=0;l<2;l++){
            int sl = s*2+l;
            k_bbA<<<256,512,0,stream>>>(e_conv, bb1_w + sl*16384, bb1_b + sl*64, t1e);
            const float* xres = (l==0) ? out_buf : conv_raw;
            k_bbB<<<256,512,0,stream>>>(t1e, xres, bb2_w + sl*32768, bb2_b + sl*128,
                                        conv_raw, e_conv);
        }
        k_qkv<<<512,256,0,stream>>>(conv_raw, qkv_w + s*4224, qkv_b + s*64,
                                    qbuf, kbuf, vbuf);
        k_attn<<<1024,256,0,stream>>>(qbuf, kbuf, vbuf, obuf);
        k_epi<<<256,256,0,stream>>>(obuf, conv_raw, out_buf,
                                    proj_w + s*2048, proj_b + s*64,
                                    outc_w + s*4096, outc_b + s*64,
                                    outa_w + s*4096, outa_b + s*64,
                                    outp_w + s*4096, outp_b + s*64,
                                    e_conv);
    }
    k_final<<<256,256,0,stream>>>(out_buf, fc_w, fc_b, logits);
}

// Round 4
// 1227.540 us; speedup vs baseline: 1.9318x; 1.3535x over previous
//
#include <hip/hip_runtime.h>
#include <math.h>

// PixelSnail forward, fp32. B=8, CH=1, H=W=32 (N=1024), HID=64, S=8, L=2,
// HEAD=4, QK=16 (d=4/head), VD=32 (8/head).

#define NPix 1024

__device__ __forceinline__ float elu_f(float x){ return x > 0.f ? x : __expf(x) - 1.f; }
__device__ __forceinline__ float sig_f(float x){ return 1.f / (1.f + __expf(-x)); }

// ---------------- weight transpose: bb1 [16][64o][64i]f4 -> [16][64i][64o]f4,
// bb2 [16][128o][64i]f4 -> [16][64i][128o]f4, qkv [8][64c][66i] -> [8][66i][64c]
__global__ __launch_bounds__(256) void k_wT(const float* __restrict__ bb1_w,
        const float* __restrict__ bb2_w, const float* __restrict__ qkv_w,
        float* __restrict__ wT1, float* __restrict__ wT2, float* __restrict__ wTq)
{
    int tid = blockIdx.x*256 + threadIdx.x;
    if (tid < 65536){
        int o = tid & 63, i = (tid>>6) & 63, sl = tid >> 12;
        reinterpret_cast<float4*>(wT1)[tid] =
            reinterpret_cast<const float4*>(bb1_w)[(sl*64 + o)*64 + i];
    }
    int t2 = tid - 65536;
    if (t2 >= 0 && t2 < 131072){
        int o = t2 & 127, i = (t2>>7) & 63, sl = t2 >> 13;
        reinterpret_cast<float4*>(wT2)[t2] =
            reinterpret_cast<const float4*>(bb2_w)[(sl*128 + o)*64 + i];
    }
    int t3 = tid - 196608;
    if (t3 >= 0 && t3 < 33792){
        int c = t3 & 63, rem = t3 >> 6, i = rem % 66, s = rem / 66;
        wTq[t3] = qkv_w[(s*64 + c)*66 + i];
    }
}

// ---------------- stem: masked 3x3 conv, 1->64, taps (0,0)(0,1)(0,2)(1,0) ----
__global__ __launch_bounds__(256) void k_stem(const float* __restrict__ x,
        const float* __restrict__ w, const float* __restrict__ bias,
        float* __restrict__ out, float* __restrict__ e_out)
{
    int b = blockIdx.x >> 5, h = blockIdx.x & 31;
    int t = threadIdx.x;
    int col = t & 31, slot = t >> 5;
    int hw = h*32 + col;
    const float* xb = x + b*NPix;
    float x00=0.f, x01=0.f, x02=0.f, x10=0.f;
    if (h > 0){
        if (col > 0)  x00 = xb[hw-33];
        x01 = xb[hw-32];
        if (col < 31) x02 = xb[hw-31];
    }
    if (col > 0) x10 = xb[hw-1];
    #pragma unroll
    for (int k2=0;k2<8;k2++){
        int o = slot*8 + k2;
        const float* wo = w + o*9;
        float v = bias[o] + wo[0]*x00 + wo[1]*x01 + wo[2]*x02 + wo[3]*x10;
        out[(b*64+o)*NPix + hw] = v;
        e_out[(b*64+o)*NPix + hw] = elu_f(v);
    }
}

// ---------------- bbA: 2x2 causal conv 64->64 on elu'd input, out = elu ----
// grid 256 = (b*16+hp)*2+half, 256 thr = 4 waves; wave = uniform out-octet,
// lane = (row r of pair, col); weights via s_load from transposed [i][64o][4]
__global__ __launch_bounds__(256) void k_bbA(const float* __restrict__ ein,
        const float* __restrict__ wT, const float* __restrict__ bias,
        float* __restrict__ t1e)
{
    __shared__ float eld[3*64*33];   // [r][i][cpos]; cpos=col+1, cpos0 = left halo = 0
    int blk = blockIdx.x;
    int half = blk & 1, hp = (blk>>1) & 15, b = blk >> 5;
    int h0 = hp*2;
    int t = threadIdx.x;
    #pragma unroll
    for (int p = 0; p < 24; p++){
        int flat = t + p*256;        // 6144 = 192 ri x 32 col
        int ri = flat >> 5, col = flat & 31;
        int r = ri >> 6, i = ri & 63;
        int row = h0 - 1 + r;
        float v = (row >= 0) ? ein[(b*64+i)*NPix + row*32 + col] : 0.f;
        eld[ri*33 + 1 + col] = v;
    }
    if (t < 192) eld[t*33] = 0.f;
    __syncthreads();
    int lam = t & 63;
    int r = lam >> 5, col = lam & 31;
    int og = __builtin_amdgcn_readfirstlane(t >> 6);
    int o0 = half*32 + og*8;
    float acc[8];
    #pragma unroll
    for (int k=0;k<8;k++) acc[k] = bias[o0+k];
    const float4* wq = reinterpret_cast<const float4*>(wT);
    const float* e0 = &eld[(r*64)*33 + col];
    const float* e1 = &eld[((r+1)*64)*33 + col];
    for (int i=0;i<64;i++){
        float a00 = e0[i*33], a01 = e0[i*33+1];
        float a10 = e1[i*33], a11 = e1[i*33+1];
        #pragma unroll
        for (int k=0;k<8;k++){
            float4 wv = wq[i*64 + o0 + k];
            acc[k] = fmaf(wv.x, a00, acc[k]);
            acc[k] = fmaf(wv.y, a01, acc[k]);
            acc[k] = fmaf(wv.z, a10, acc[k]);
            acc[k] = fmaf(wv.w, a11, acc[k]);
        }
    }
    int gi = (b*64 + o0)*NPix + (h0 + r)*32 + col;
    #pragma unroll
    for (int k=0;k<8;k++)
        t1e[gi + k*NPix] = elu_f(acc[k]);
}

// ---------------- bbB: 2x2 conv 64->128 + gate x + x1*sig(x2) ----
// grid 256, 512 thr = 8 waves: waves 0-3 x1-octets, 4-7 x2-octets
__global__ __launch_bounds__(512) void k_bbB(const float* __restrict__ ein,
        const float* __restrict__ xres, const float* __restrict__ wT,
        const float* __restrict__ bias,
        float* __restrict__ conv_out, float* __restrict__ e_out)
{
    __shared__ float eld[3*64*33];
    __shared__ float obuf[64*64];    // [0..31]=x1 local, [32..63]=x2 local
    int blk = blockIdx.x;
    int half = blk & 1, hp = (blk>>1) & 15, b = blk >> 5;
    int h0 = hp*2;
    int t = threadIdx.x;
    #pragma unroll
    for (int p = 0; p < 12; p++){
        int flat = t + p*512;
        int ri = flat >> 5, col = flat & 31;
        int r = ri >> 6, i = ri & 63;
        int row = h0 - 1 + r;
        float v = (row >= 0) ? ein[(b*64+i)*NPix + row*32 + col] : 0.f;
        eld[ri*33 + 1 + col] = v;
    }
    if (t < 192) eld[t*33] = 0.f;
    __syncthreads();
    int lam = t & 63;
    int r = lam >> 5, col = lam & 31;
    int wv8 = __builtin_amdgcn_readfirstlane(t >> 6);
    int part = wv8 >> 2;             // 0: x1 (ch 0-63), 1: x2 (ch 64-127)
    int og = wv8 & 3;
    int o = part*64 + half*32 + og*8;
    float acc[8];
    #pragma unroll
    for (int k=0;k<8;k++) acc[k] = bias[o+k];
    const float4* wq = reinterpret_cast<const float4*>(wT);
    const float* e0 = &eld[(r*64)*33 + col];
    const float* e1 = &eld[((r+1)*64)*33 + col];
    for (int i=0;i<64;i++){
        float a00 = e0[i*33], a01 = e0[i*33+1];
        float a10 = e1[i*33], a11 = e1[i*33+1];
        #pragma unroll
        for (int k=0;k<8;k++){
            float4 wv = wq[i*128 + o + k];
            acc[k] = fmaf(wv.x, a00, acc[k]);
            acc[k] = fmaf(wv.y, a01, acc[k]);
            acc[k] = fmaf(wv.z, a10, acc[k]);
            acc[k] = fmaf(wv.w, a11, acc[k]);
        }
    }
    #pragma unroll
    for (int k=0;k<8;k++) obuf[(part*32 + og*8 + k)*64 + lam] = acc[k];
    __syncthreads();
    #pragma unroll
    for (int p=0;p<4;p++){
        int idx = t + p*512;         // 2048 = 32 o_local x 64 px
        int ol = idx >> 6, px = idx & 63;
        float x1 = obuf[ol*64 + px], x2 = obuf[(32+ol)*64 + px];
        int oc = half*32 + ol;
        int gi = (b*64+oc)*NPix + (h0 + (px>>5))*32 + (px&31);
        float v = fmaf(x1, sig_f(x2), xres[gi]);
        conv_out[gi] = v;
        e_out[gi] = elu_f(v);
    }
}

// ---------------- qkv 1x1: (conv 64ch + pos 2ch) -> q/k/v head layouts ----
// grid 256 = (b*16+tile)*2+ohalf, 256 thr = 4 waves; wave = uniform out-octet,
// lane = px in 64-px tile; weights via s_load from transposed [66i][64c]
__global__ __launch_bounds__(256) void k_qkv(const float* __restrict__ conv,
        const float* __restrict__ wt, const float* __restrict__ bias,
        float* __restrict__ qb, float* __restrict__ kb, float* __restrict__ vb)
{
    __shared__ float cl[66*64];
    int blk = blockIdx.x;
    int ohalf = blk & 1, tile = (blk>>1) & 15, b = blk >> 5;
    int hw0 = tile*64;
    int t = threadIdx.x;
    #pragma unroll
    for (int p=0;p<16;p++){
        int idx = t + p*256;
        int i = idx >> 6, px = idx & 63;
        cl[i*64 + px] = conv[(b*64+i)*NPix + hw0 + px];
    }
    if (t < 128){
        int px = t & 63;
        int hw = hw0 + px;
        float v = (t < 64) ? ((float)(hw>>5)*(1.f/32.f) - 0.5f)
                           : ((float)(hw&31)*(1.f/32.f) - 0.5f);
        cl[(64 + (t>>6))*64 + px] = v;
    }
    __syncthreads();
    int px = t & 63;
    int og = __builtin_amdgcn_readfirstlane(t >> 6);
    int c0 = ohalf*32 + og*8;
    int hw = hw0 + px;
    float acc[8];
    #pragma unroll
    for (int k=0;k<8;k++) acc[k] = bias[c0+k];
    for (int i=0;i<66;i++){
        float e = cl[i*64 + px];
        #pragma unroll
        for (int k=0;k<8;k++)
            acc[k] = fmaf(wt[i*64 + c0 + k], e, acc[k]);
    }
    float4 f0 = {acc[0],acc[1],acc[2],acc[3]};
    float4 f1 = {acc[4],acc[5],acc[6],acc[7]};
    if (c0 < 32){
        float* dst = (c0 < 16) ? qb : kb;
        int cc = c0 & 15;
        reinterpret_cast<float4*>(dst)[(b*4 + (cc>>2))*NPix + hw] = f0;
        reinterpret_cast<float4*>(dst)[(b*4 + (cc>>2) + 1)*NPix + hw] = f1;
    } else {
        int c2 = c0 - 32;
        reinterpret_cast<float4*>(vb)[((b*4 + (c2>>3))*NPix + hw)*2]     = f0;
        reinterpret_cast<float4*>(vb)[((b*4 + (c2>>3))*NPix + hw)*2 + 1] = f1;
    }
}

// ---------------- causal attention: single pass (no max-sub; scores O(1)),
// 2 queries per 8-lane slot. grid 512 = bh*16 + r16, 256 thr.
__global__ __launch_bounds__(256) void k_attn(const float* __restrict__ qb,
        const float* __restrict__ kb, const float* __restrict__ vb,
        float* __restrict__ ob)
{
    int bh = blockIdx.x >> 4, r16 = blockIdx.x & 15;
    int t = threadIdx.x;
    int s = t >> 3, sub = t & 7;
    int qa = r16 + 32*s, qbq = qa + 16;
    const float4* k4 = reinterpret_cast<const float4*>(kb) + bh*NPix;
    const float4* v4 = reinterpret_cast<const float4*>(vb) + bh*NPix*2;
    float4 qva = reinterpret_cast<const float4*>(qb)[bh*NPix + qa];
    float4 qvb = reinterpret_cast<const float4*>(qb)[bh*NPix + qbq];
    float lsa = 0.f, lsb = 0.f;
    float4 a0={0,0,0,0}, a1={0,0,0,0}, b0={0,0,0,0}, b1={0,0,0,0};
    for (int j = sub; j <= qbq; j += 8){
        float4 kk = k4[j];
        float sa = 0.5f*(qva.x*kk.x + qva.y*kk.y + qva.z*kk.z + qva.w*kk.w);
        float sb = 0.5f*(qvb.x*kk.x + qvb.y*kk.y + qvb.z*kk.z + qvb.w*kk.w);
        float pa = (j <= qa) ? __expf(sa) : 0.f;
        float pb = __expf(sb);
        lsa += pa; lsb += pb;
        float4 v0 = v4[2*j], v1 = v4[2*j+1];
        a0.x = fmaf(pa, v0.x, a0.x); a0.y = fmaf(pa, v0.y, a0.y);
        a0.z = fmaf(pa, v0.z, a0.z); a0.w = fmaf(pa, v0.w, a0.w);
        a1.x = fmaf(pa, v1.x, a1.x); a1.y = fmaf(pa, v1.y, a1.y);
        a1.z = fmaf(pa, v1.z, a1.z); a1.w = fmaf(pa, v1.w, a1.w);
        b0.x = fmaf(pb, v0.x, b0.x); b0.y = fmaf(pb, v0.y, b0.y);
        b0.z = fmaf(pb, v0.z, b0.z); b0.w = fmaf(pb, v0.w, b0.w);
        b1.x = fmaf(pb, v1.x, b1.x); b1.y = fmaf(pb, v1.y, b1.y);
        b1.z = fmaf(pb, v1.z, b1.z); b1.w = fmaf(pb, v1.w, b1.w);
    }
    #pragma unroll
    for (int off=1; off<8; off<<=1){
        lsa  += __shfl_xor(lsa, off);  lsb  += __shfl_xor(lsb, off);
        a0.x += __shfl_xor(a0.x, off); a0.y += __shfl_xor(a0.y, off);
        a0.z += __shfl_xor(a0.z, off); a0.w += __shfl_xor(a0.w, off);
        a1.x += __shfl_xor(a1.x, off); a1.y += __shfl_xor(a1.y, off);
        a1.z += __shfl_xor(a1.z, off); a1.w += __shfl_xor(a1.w, off);
        b0.x += __shfl_xor(b0.x, off); b0.y += __shfl_xor(b0.y, off);
        b0.z += __shfl_xor(b0.z, off); b0.w += __shfl_xor(b0.w, off);
        b1.x += __shfl_xor(b1.x, off); b1.y += __shfl_xor(b1.y, off);
        b1.z += __shfl_xor(b1.z, off); b1.w += __shfl_xor(b1.w, off);
    }
    if (sub == 0){
        float ia = 1.f/lsa, ib = 1.f/lsb;
        float4* od = reinterpret_cast<float4*>(ob);
        float4 ra0 = {a0.x*ia, a0.y*ia, a0.z*ia, a0.w*ia};
        float4 ra1 = {a1.x*ia, a1.y*ia, a1.z*ia, a1.w*ia};
        float4 rb0 = {b0.x*ib, b0.y*ib, b0.z*ib, b0.w*ib};
        float4 rb1 = {b1.x*ib, b1.y*ib, b1.z*ib, b1.w*ib};
        od[(bh*NPix + qa)*2]      = ra0;
        od[(bh*NPix + qa)*2 + 1]  = ra1;
        od[(bh*NPix + qbq)*2]     = rb0;
        od[(bh*NPix + qbq)*2 + 1] = rb1;
    }
}

// ---------------- epilogue: proj -> outa | outc | outp chain + residual ----
// grid 256 = b*32 + tile32; all four weight matrices staged in LDS.
__global__ __launch_bounds__(256) void k_epi(const float* __restrict__ ob,
        const float* __restrict__ conv_raw, float* __restrict__ out,
        const float* __restrict__ pw,  const float* __restrict__ pb,
        const float* __restrict__ cw,  const float* __restrict__ cb2,
        const float* __restrict__ aw,  const float* __restrict__ ab,
        const float* __restrict__ ppw, const float* __restrict__ ppb,
        float* __restrict__ e_out)
{
    __shared__ float s_x[64][33];
    __shared__ float s_ov[32][33];
    __shared__ float s_e1[64][33];
    __shared__ float s_g[64][33];
    __shared__ float wl[14336];   // pw@0(2048), cw@2048(4096), aw@6144(4096), ppw@10240(4096)
    int b = blockIdx.x >> 5;
    int hw0 = (blockIdx.x & 31) * 32;
    int t = threadIdx.x;
    for (int idx = t; idx < 64*32; idx += 256){
        int i = idx >> 5, px = idx & 31;
        s_x[i][px] = elu_f(conv_raw[(b*64+i)*NPix + hw0 + px]);
    }
    for (int idx = t; idx < 32*32; idx += 256){
        int c = idx >> 5, px = idx & 31;
        s_ov[c][px] = ob[(b*4 + (c>>3))*NPix*8 + (hw0+px)*8 + (c&7)];
    }
    {
        float4* wl4 = reinterpret_cast<float4*>(wl);
        for (int idx = t; idx < 512; idx += 256)
            wl4[idx] = reinterpret_cast<const float4*>(pw)[idx];
        for (int idx = t; idx < 1024; idx += 256){
            wl4[512 + idx]  = reinterpret_cast<const float4*>(cw)[idx];
            wl4[1536 + idx] = reinterpret_cast<const float4*>(aw)[idx];
            wl4[2560 + idx] = reinterpret_cast<const float4*>(ppw)[idx];
        }
    }
    __syncthreads();
    int px = t & 31, g = t >> 5;
    int o0 = g*8;
    const float4* wp4  = reinterpret_cast<const float4*>(wl);
    const float4* wc4  = reinterpret_cast<const float4*>(wl + 2048);
    const float4* wa4  = reinterpret_cast<const float4*>(wl + 6144);
    const float4* wpp4 = reinterpret_cast<const float4*>(wl + 10240);
    // proj: 32 -> 64
    float acc[8];
    #pragma unroll
    for (int k=0;k<8;k++) acc[k] = pb[o0+k];
    #pragma unroll
    for (int i4=0;i4<8;i4++){
        float v0 = s_ov[i4*4+0][px], v1 = s_ov[i4*4+1][px];
        float v2 = s_ov[i4*4+2][px], v3 = s_ov[i4*4+3][px];
        #pragma unroll
        for (int k=0;k<8;k++){
            float4 wv = wp4[(o0+k)*8 + i4];
            acc[k] = fmaf(wv.x, v0, acc[k]); acc[k] = fmaf(wv.y, v1, acc[k]);
            acc[k] = fmaf(wv.z, v2, acc[k]); acc[k] = fmaf(wv.w, v3, acc[k]);
        }
    }
    #pragma unroll
    for (int k=0;k<8;k++) s_e1[o0+k][px] = elu_f(acc[k]);
    __syncthreads();
    // outa(e1), outc(x): 64 -> 64 each
    float aa[8], cc[8];
    #pragma unroll
    for (int k=0;k<8;k++){ aa[k] = ab[o0+k]; cc[k] = cb2[o0+k]; }
    #pragma unroll
    for (int i4=0;i4<16;i4++){
        float e0 = s_e1[i4*4+0][px], e1 = s_e1[i4*4+1][px];
        float e2 = s_e1[i4*4+2][px], e3 = s_e1[i4*4+3][px];
        float x0 = s_x[i4*4+0][px],  x1 = s_x[i4*4+1][px];
        float x2 = s_x[i4*4+2][px],  x3 = s_x[i4*4+3][px];
        #pragma unroll
        for (int k=0;k<8;k++){
            float4 wa = wa4[(o0+k)*16 + i4];
            float4 wc = wc4[(o0+k)*16 + i4];
            aa[k] = fmaf(wa.x, e0, aa[k]); aa[k] = fmaf(wa.y, e1, aa[k]);
            aa[k] = fmaf(wa.z, e2, aa[k]); aa[k] = fmaf(wa.w, e3, aa[k]);
            cc[k] = fmaf(wc.x, x0, cc[k]); cc[k] = fmaf(wc.y, x1, cc[k]);
            cc[k] = fmaf(wc.z, x2, cc[k]); cc[k] = fmaf(wc.w, x3, cc[k]);
        }
    }
    #pragma unroll
    for (int k=0;k<8;k++) s_g[o0+k][px] = elu_f(elu_f(aa[k]) + elu_f(cc[k]));
    __syncthreads();
    // outp: 64 -> 64, residual, final elu
    float bl[8];
    #pragma unroll
    for (int k=0;k<8;k++) bl[k] = ppb[o0+k];
    #pragma unroll
    for (int i4=0;i4<16;i4++){
        float g0 = s_g[i4*4+0][px], g1 = s_g[i4*4+1][px];
        float g2 = s_g[i4*4+2][px], g3 = s_g[i4*4+3][px];
        #pragma unroll
        for (int k=0;k<8;k++){
            float4 wv = wpp4[(o0+k)*16 + i4];
            bl[k] = fmaf(wv.x, g0, bl[k]); bl[k] = fmaf(wv.y, g1, bl[k]);
            bl[k] = fmaf(wv.z, g2, bl[k]); bl[k] = fmaf(wv.w, g3, bl[k]);
        }
    }
    #pragma unroll
    for (int k=0;k<8;k++){
        int gi = (b*64 + o0 + k)*NPix + hw0 + px;
        float on = elu_f(bl[k]) + out[gi];
        out[gi] = on;
        e_out[gi] = elu_f(on);
    }
}

// ---------------- final 1x1: logits = fc_w . elu(out) + fc_b ----
__global__ __launch_bounds__(256) void k_final(const float* __restrict__ out,
        const float* __restrict__ fw, const float* __restrict__ fb,
        float* __restrict__ logits)
{
    int idx = blockIdx.x*256 + threadIdx.x;      // 65536
    int pix = idx >> 3, sub = idx & 7;
    int b = pix >> 10, hw = pix & 1023;
    const float* obp = out + b*64*NPix + hw;
    float acc = 0.f;
    #pragma unroll
    for (int k=0;k<8;k++){
        int i = sub*8 + k;
        acc = fmaf(fw[i], elu_f(obp[i*NPix]), acc);
    }
    #pragma unroll
    for (int off=1; off<8; off<<=1) acc += __shfl_xor(acc, off);
    if (sub == 0) logits[pix] = acc + fb[0];
}

extern "C" void kernel_launch(void* const* d_in, const int* in_sizes, int n_in,
                              void* d_out, int out_size, void* d_ws, size_t ws_size,
                              hipStream_t stream)
{
    const float* x      = (const float*)d_in[0];
    const float* stem_w = (const float*)d_in[1];
    const float* stem_b = (const float*)d_in[2];
    const float* bb1_w  = (const float*)d_in[3];
    const float* bb1_b  = (const float*)d_in[4];
    const float* bb2_w  = (const float*)d_in[5];
    const float* bb2_b  = (const float*)d_in[6];
    const float* qkv_w  = (const float*)d_in[7];
    const float* qkv_b  = (const float*)d_in[8];
    const float* proj_w = (const float*)d_in[9];
    const float* proj_b = (const float*)d_in[10];
    const float* outc_w = (const float*)d_in[11];
    const float* outc_b = (const float*)d_in[12];
    const float* outa_w = (const float*)d_in[13];
    const float* outa_b = (const float*)d_in[14];
    const float* outp_w = (const float*)d_in[15];
    const float* outp_b = (const float*)d_in[16];
    const float* fc_w   = (const float*)d_in[17];
    const float* fc_b   = (const float*)d_in[18];
    float* logits = (float*)d_out;

    float* W        = (float*)d_ws;
    float* out_buf  = W;                  // B*64*N = 524288
    float* e_conv   = W + 524288;
    float* conv_raw = W + 2*524288;
    float* t1e      = W + 3*524288;
    float* qbuf     = W + 4*524288;       // [b][h][n][4]
    float* kbuf     = qbuf + 131072;
    float* vbuf     = kbuf + 131072;      // [b][h][n][8]
    float* obuf     = vbuf + 262144;      // [b][h][n][8]
    float* wT1      = obuf + 262144;      // 16*64*64*4 = 262144
    float* wT2      = wT1 + 262144;       // 16*64*128*4 = 524288
    float* wTq      = wT2 + 524288;       // 8*66*64 = 33792

    k_wT<<<900,256,0,stream>>>(bb1_w, bb2_w, qkv_w, wT1, wT2, wTq);
    k_stem<<<256,256,0,stream>>>(x, stem_w, stem_b, out_buf, e_conv);
    for (int s=0;s<8;s++){
        for (int l=0;l<2;l++){
            int sl = s*2+l;
            k_bbA<<<256,256,0,stream>>>(e_conv, wT1 + sl*16384, bb1_b + sl*64, t1e);
            const float* xres = (l==0) ? out_buf : conv_raw;
            k_bbB<<<256,512,0,stream>>>(t1e, xres, wT2 + sl*32768, bb2_b + sl*128,
                                        conv_raw, e_conv);
        }
        k_qkv<<<256,256,0,stream>>>(conv_raw, wTq + s*4224, qkv_b + s*64,
                                    qbuf, kbuf, vbuf);
        k_attn<<<512,256,0,stream>>>(qbuf, kbuf, vbuf, obuf);
        k_epi<<<256,256,0,stream>>>(obuf, conv_raw, out_buf,
                                    proj_w + s*2048, proj_b + s*64,
                                    outc_w + s*4096, outc_b + s*64,
                                    outa_w + s*4096, outa_b + s*64,
                                    outp_w + s*4096, outp_b + s*64,
                                    e_conv);
    }
    k_final<<<256,256,0,stream>>>(out_buf, fc_w, fc_b, logits);
}